// Round 22
// baseline (1015.759 us; speedup 1.0000x reference)
//
#include <hip/hip_runtime.h>
#include <cfloat>

#define N_PTS 4096
#define NB    4
#define KNN   20
#define EPSB  1e-5f
#define NSL   8          // knn candidate slices per batch-row (R22: 8 w/ LDS union)

typedef short s8v __attribute__((ext_vector_type(8)));
typedef float f4v __attribute__((ext_vector_type(4)));

// ---------------------------------------------------------------------------
// bf16 hi/lo split (round-to-nearest-even both halves)
// ---------------------------------------------------------------------------
__device__ __forceinline__ void bf16split(float x, unsigned short* h, unsigned short* l)
{
    unsigned u = __builtin_bit_cast(unsigned, x);
    unsigned hb = (u + 0x7fffu + ((u >> 16) & 1u)) >> 16;
    float hf = __builtin_bit_cast(float, hb << 16);
    float res = x - hf;
    unsigned u2 = __builtin_bit_cast(unsigned, res);
    unsigned lb = (u2 + 0x7fffu + ((u2 >> 16) & 1u)) >> 16;
    *h = (unsigned short)hb;
    *l = (unsigned short)lb;
}

// ---------------------------------------------------------------------------
// Packed key: fp32 distance (top 24 bits) | 8-bit lane-local ordinal.
// 15 mantissa bits: R10's 11-bit variant FAILED (0.44); this passed (0.03).
// ---------------------------------------------------------------------------
__device__ __forceinline__ unsigned packkey(float d, int lc)
{
    d = fmaxf(d, 0.f);
    unsigned u = __builtin_bit_cast(unsigned, d);
    return (u & 0xFFFFFF00u) | (unsigned)lc;
}

// Branch-free sorted-insert: ascending bubble, 20x (v_min_u32 + v_max_u32).
__device__ __forceinline__ void insert20k(unsigned key, unsigned (&k20)[KNN])
{
#pragma unroll
    for (int j = 0; j < KNN; j++) {
        unsigned old = k20[j];
        unsigned lo = old < key ? old : key;
        key = old < key ? key : old;
        k20[j] = lo;
    }
}

// async global->LDS, 16B per lane; LDS dest = wave-uniform base + lane*16
__device__ __forceinline__ void gl2lds16(const void* g, void* l)
{
    __builtin_amdgcn_global_load_lds(
        (const __attribute__((address_space(1))) unsigned int*)g,
        (__attribute__((address_space(3))) unsigned int*)l,
        16, 0, 0);
}

// 16B-chunk swizzle (involution): chunk g lives at LDS chunk g ^ f(g).
__device__ __forceinline__ int swz(int g)
{
    return g ^ (((g >> 3) ^ (g >> 6)) & 7);
}

// ---------------------------------------------------------------------------
// Point-major fp32 -> bf16 hi/lo (stage-0 only: x, C=3 -> KDP=32).
// ---------------------------------------------------------------------------
__global__ __launch_bounds__(256)
void to_bf16_pm(const float* __restrict__ F, long bsF, int ldF, int C, int KDP,
                unsigned short* __restrict__ Ghi, unsigned short* __restrict__ Glo)
{
    int b = blockIdx.y;
    int n = blockIdx.x * 64 + (threadIdx.x & 63);
    int kq = threadIdx.x >> 6;
    const float* Fr = F + (long)b * bsF + (long)n * ldF;
    for (int k0 = kq * 8; k0 < KDP; k0 += 32) {
        s8v hv, lv;
#pragma unroll
        for (int i = 0; i < 8; i++) {
            int k = k0 + i;
            float x = (k < C) ? Fr[k] : 0.f;
            unsigned short h, l;
            bf16split(x, &h, &l);
            hv[i] = (short)h;
            lv[i] = (short)l;
        }
        long o = ((long)b * N_PTS + n) * KDP + k0;
        *(s8v*)&Ghi[o] = hv;
        *(s8v*)&Glo[o] = lv;
    }
}

__global__ void sqnorm_pm(const float* __restrict__ F, float* __restrict__ xx,
                          int C, int ldF, long bsF)
{
    int b = blockIdx.y;
    int i = blockIdx.x * 256 + threadIdx.x;
    const float* r = F + (long)b * bsF + (long)i * ldF;
    float s = 0.f;
    for (int c = 0; c < C; c++) s = fmaf(r[c], r[c], s);
    xx[(long)b * N_PTS + i] = s;
}

// ---------------------------------------------------------------------------
// MFMA fused distance + top-20, LDS-staged + XOR swizzle, v8 (R22):
// cbuf/mk LDS UNION -> 20,480 B exactly = 160 KiB / 8 -> 8 blocks/CU,
// fed by NSL=8 (grid 2048 = 8/CU). mk (merge scratch) is only live after
// the t-loop when cbuf is dead; overlaying them removes the 36,864 B
// footprint that capped R21 at 4 blocks/CU (65% VALUBusy, 35% stall).
// Staged candidate traffic is invariant vs NSL=4 (each block stages only
// its own slice); total insert issue invariant (lanes x2, cands/lane /2).
// Slice = 512 candidates (32 tiles of 16); lc = t*4+r <= 127 (8-bit field).
// ---------------------------------------------------------------------------
template<int KDP>
__global__ __launch_bounds__(256, 3)
void fused_knn_mfma8(const unsigned short* __restrict__ Ghi,
                     const unsigned short* __restrict__ Glo,
                     const float* __restrict__ xx,
                     float* __restrict__ knnd, int* __restrict__ knni)
{
    constexpr int KS = KDP / 32;
    constexpr int TS = 16 * KDP;          // shorts per tile per array
    constexpr int NCH = (TS * 2) / 16;    // 16B chunks per array per tile
    __shared__ __align__(16) char smem[20480];
    short* cbuf = (short*)smem;                    // [2][2][TS] <= 16,384 B
    unsigned* mk = (unsigned*)smem;                // [4][16][4][KNN] = 20,480 B

    int tid = threadIdx.x;
    int w = tid >> 6, L = tid & 63;
    int n = L & 15;
    int quad = L >> 4;
    int b = blockIdx.z, slice = blockIdx.y;
    int q0 = blockIdx.x * 64, qw = w * 16;
    const unsigned short* Gh = Ghi + (long)b * N_PTS * KDP;
    const unsigned short* Gl = Glo + (long)b * N_PTS * KDP;
    const float* xxb = xx + (long)b * N_PTS;

    // persistent query fragments (global, once)
    s8v qhi[KS], qlo[KS];
    long qbase = (long)(q0 + qw + n) * KDP + quad * 8;
#pragma unroll
    for (int ks = 0; ks < KS; ks++) {
        qhi[ks] = *(const s8v*)&Gh[qbase + ks * 32];
        qlo[ks] = *(const s8v*)&Gl[qbase + ks * 32];
    }
    float xq = xxb[q0 + qw + n];

    unsigned k20[KNN];
#pragma unroll
    for (int j = 0; j < KNN; j++) k20[j] = 0xFFFFFFFFu;

    // swizzled fragment chunk positions (shorts offset = chunk*8)
    int po[KS];
#pragma unroll
    for (int ks = 0; ks < KS; ks++) {
        int gL = n * (KDP / 8) + quad + ks * 4;
        po[ks] = swz(gL) * 8;
    }
    int gsrc = swz(tid);                  // staging source chunk (involution)

    int w64 = tid & 192;                  // wave base (uniform per wave)
    // prologue: stage tile 0 into buf 0
    {
        long tb = (long)(slice * 512) * KDP;
        if (tid < NCH) {
            gl2lds16((const char*)(Gh + tb) + gsrc * 16,
                     (char*)(cbuf + 0 * 2 * TS + 0 * TS) + w64 * 16);
            gl2lds16((const char*)(Gl + tb) + gsrc * 16,
                     (char*)(cbuf + 0 * 2 * TS + 1 * TS) + w64 * 16);
        }
    }
    __syncthreads();

    const float* xcp = xxb + slice * 512 + quad * 4;

    for (int t = 0; t < 32; t++) {
        int cur = t & 1;
        // prefetch tile t+1 into the other buffer (async DMA)
        if (t < 31 && tid < NCH) {
            long tb = (long)(slice * 512 + (t + 1) * 16) * KDP;
            gl2lds16((const char*)(Gh + tb) + gsrc * 16,
                     (char*)(cbuf + (cur ^ 1) * 2 * TS + 0 * TS) + w64 * 16);
            gl2lds16((const char*)(Gl + tb) + gsrc * 16,
                     (char*)(cbuf + (cur ^ 1) * 2 * TS + 1 * TS) + w64 * 16);
        }

        // compute on current tile from LDS (swizzled fragment reads)
        const short* Ch = cbuf + cur * 2 * TS;
        const short* Cl = Ch + TS;
        f4v acc = {0.f, 0.f, 0.f, 0.f};
#pragma unroll
        for (int ks = 0; ks < KS; ks++) {
            s8v chi = *(const s8v*)&Ch[po[ks]];
            s8v clo = *(const s8v*)&Cl[po[ks]];
            acc = __builtin_amdgcn_mfma_f32_16x16x32_bf16(chi, qhi[ks], acc, 0, 0, 0);
            acc = __builtin_amdgcn_mfma_f32_16x16x32_bf16(chi, qlo[ks], acc, 0, 0, 0);
            acc = __builtin_amdgcn_mfma_f32_16x16x32_bf16(clo, qhi[ks], acc, 0, 0, 0);
        }
        float4 xc4 = *(const float4*)xcp;
        float xcv[4] = {xc4.x, xc4.y, xc4.z, xc4.w};
#pragma unroll
        for (int r = 0; r < 4; r++) {
            float d = xq + xcv[r] - 2.f * acc[r];
            insert20k(packkey(d, t * 4 + r), k20);
        }
        xcp += 16;
        __syncthreads();   // drains prefetch DMA + frees cur buffer
    }
    // cbuf dead from here; mk (union) takes over after the barrier above

    // publish per-lane lists, then 16 owner lanes merge 4 quad-slices/query
#pragma unroll
    for (int j = 0; j < KNN; j++)
        mk[((w * 16 + n) * 4 + quad) * KNN + j] = k20[j];
    __syncthreads();
    if (L < 16) {
        int p[4] = {0, 0, 0, 0};
        long o = (((long)b * NSL + slice) * N_PTS + (q0 + qw + L)) * KNN;
#pragma unroll
        for (int j = 0; j < KNN; j++) {
            unsigned bd = 0xFFFFFF00u; int bi = 0x7fffffff; int bq = 0;
#pragma unroll
            for (int qd = 0; qd < 4; qd++) {
                unsigned kk = mk[((w * 16 + L) * 4 + qd) * KNN + p[qd]];
                unsigned db = kk & 0xFFFFFF00u;
                int lc = (int)(kk & 0xFFu);
                int ci = slice * 512 + (lc >> 2) * 16 + qd * 4 + (lc & 3);
                if (db < bd || (db == bd && ci < bi)) { bd = db; bi = ci; bq = qd; }
            }
            knnd[o + j] = __builtin_bit_cast(float, bd);
            knni[o + j] = bi;
            p[bq]++;
        }
    }
}

// ---------------------------------------------------------------------------
// Merge the NSL sorted slice lists per query -> final idx[b][i][KNN].
// Ties (equal truncated distance) broken by lower global index.
// ---------------------------------------------------------------------------
__global__ void knn_merge8(const float* __restrict__ knnd, const int* __restrict__ knni,
                           int* __restrict__ idxOut)
{
    int id = blockIdx.x * 256 + threadIdx.x;
    int b = id / N_PTS, i = id % N_PTS;
    const float* dl[NSL]; const int* il[NSL];
#pragma unroll
    for (int qt = 0; qt < NSL; qt++) {
        dl[qt] = knnd + (((long)b * NSL + qt) * N_PTS + i) * KNN;
        il[qt] = knni + (((long)b * NSL + qt) * N_PTS + i) * KNN;
    }
    int p[NSL];
#pragma unroll
    for (int qt = 0; qt < NSL; qt++) p[qt] = 0;
    int* o = idxOut + (long)id * KNN;
#pragma unroll
    for (int j = 0; j < KNN; j++) {
        float best = FLT_MAX; int bi = 0x7fffffff; int bq = 0;
#pragma unroll
        for (int qt = 0; qt < NSL; qt++) {
            float vv = (p[qt] < KNN) ? dl[qt][p[qt]] : FLT_MAX;
            int   ci = (p[qt] < KNN) ? il[qt][p[qt]] : 0x7fffffff;
            if (vv < best || (vv == best && ci < bi)) { best = vv; bi = ci; bq = qt; }
        }
        o[j] = bi;
        p[bq]++;
    }
}

// ---------------------------------------------------------------------------
// Fused q/p MFMA GEMM (edge stages) — unchanged.
// ---------------------------------------------------------------------------
template<int KDP>
__global__ __launch_bounds__(256)
void qp_mfma(const unsigned short* __restrict__ Ghi,
             const unsigned short* __restrict__ Glo,
             const unsigned short* __restrict__ Wqh, const unsigned short* __restrict__ Wql,
             const unsigned short* __restrict__ Wph, const unsigned short* __restrict__ Wpl,
             const float* __restrict__ shf,
             float* __restrict__ qv, float* __restrict__ pv, int cout)
{
    constexpr int KS = KDP / 32;
    int tid = threadIdx.x;
    int w = tid >> 6, L = tid & 63;
    int n = L & 15, quad = L >> 4;
    int b = blockIdx.z;
    int p0 = blockIdx.x * 64 + w * 16;

    s8v ah[KS], al[KS];
    long abase = ((long)b * N_PTS + p0 + n) * KDP + quad * 8;
#pragma unroll
    for (int ks = 0; ks < KS; ks++) {
        ah[ks] = *(const s8v*)&Ghi[abase + ks * 32];
        al[ks] = *(const s8v*)&Glo[abase + ks * 32];
    }

#pragma unroll
    for (int oc4 = 0; oc4 < 4; oc4++) {
        int oc = blockIdx.y * 4 + oc4;
        long wbase = (long)(oc * 16 + n) * KDP + quad * 8;
        f4v aq = {0.f, 0.f, 0.f, 0.f};
        f4v ap = {0.f, 0.f, 0.f, 0.f};
#pragma unroll
        for (int ks = 0; ks < KS; ks++) {
            s8v wh = *(const s8v*)&Wqh[wbase + ks * 32];
            s8v wl = *(const s8v*)&Wql[wbase + ks * 32];
            aq = __builtin_amdgcn_mfma_f32_16x16x32_bf16(ah[ks], wh, aq, 0, 0, 0);
            aq = __builtin_amdgcn_mfma_f32_16x16x32_bf16(ah[ks], wl, aq, 0, 0, 0);
            aq = __builtin_amdgcn_mfma_f32_16x16x32_bf16(al[ks], wh, aq, 0, 0, 0);
            s8v ph = *(const s8v*)&Wph[wbase + ks * 32];
            s8v pl = *(const s8v*)&Wpl[wbase + ks * 32];
            ap = __builtin_amdgcn_mfma_f32_16x16x32_bf16(ah[ks], ph, ap, 0, 0, 0);
            ap = __builtin_amdgcn_mfma_f32_16x16x32_bf16(ah[ks], pl, ap, 0, 0, 0);
            ap = __builtin_amdgcn_mfma_f32_16x16x32_bf16(al[ks], ph, ap, 0, 0, 0);
        }
        float sv = shf[oc * 16 + n];
#pragma unroll
        for (int r = 0; r < 4; r++) {
            long pt = p0 + quad * 4 + r;
            long o = ((long)b * N_PTS + pt) * cout + oc * 16 + n;
            qv[o] = aq[r];
            pv[o] = ap[r] + sv;
        }
    }
}

// ---------------------------------------------------------------------------
// Stage-4 conv, LDS double-buffered W + cat tiles (R21, unchanged).
// ---------------------------------------------------------------------------
__global__ __launch_bounds__(256)
void conv4h_mfma(const float* __restrict__ cat,
                 const unsigned short* __restrict__ W4h, const unsigned short* __restrict__ W4l,
                 const float* __restrict__ shf, float* __restrict__ Y)
{
    __shared__ short Wbs[2][2][2048];
    __shared__ float Cbs[2][2048];

    int tid = threadIdx.x;
    int w = tid >> 6, L = tid & 63;
    int n = L & 15, quad = L >> 4;
    int b = blockIdx.z;
    int p0b = blockIdx.x * 64;
    int ob0 = blockIdx.y * 64;
    int w64 = tid & 192;

    const char* catb = (const char*)(cat + ((long)b * N_PTS + p0b) * 512);
    const char* whb  = (const char*)(W4h + (long)ob0 * 512);
    const char* wlb  = (const char*)(W4l + (long)ob0 * 512);

    int gw = swz(tid);
    int gc0 = swz(tid);
    int gc1 = swz(tid + 256);

    long woff = (long)(gw >> 2) * 1024 + (gw & 3) * 16;
    long coff0 = (long)(gc0 >> 3) * 2048 + (gc0 & 7) * 16;
    long coff1 = (long)(gc1 >> 3) * 2048 + (gc1 & 7) * 16;

    {
        gl2lds16(whb + woff, (char*)&Wbs[0][0][0] + w64 * 16);
        gl2lds16(wlb + woff, (char*)&Wbs[0][1][0] + w64 * 16);
        gl2lds16(catb + coff0, (char*)&Cbs[0][0] + w64 * 16);
        gl2lds16(catb + coff1, (char*)&Cbs[0][0] + (256 + w64) * 16);
    }
    __syncthreads();

    int p8 = (w * 16 + n) * 8;
    int cch0 = swz(p8 + quad * 2) * 16;
    int cch1 = swz(p8 + quad * 2 + 1) * 16;
    int wch[4];
#pragma unroll
    for (int c4 = 0; c4 < 4; c4++) wch[c4] = swz((c4 * 16 + n) * 4 + quad) * 16;

    f4v acc[4];
#pragma unroll
    for (int c4 = 0; c4 < 4; c4++) acc[c4] = {0.f, 0.f, 0.f, 0.f};

    for (int ks = 0; ks < 16; ks++) {
        int cur = ks & 1;
        if (ks < 15) {
            long t2 = (long)(ks + 1) * 64;
            long tc = (long)(ks + 1) * 128;
            gl2lds16(whb + t2 + woff, (char*)&Wbs[cur ^ 1][0][0] + w64 * 16);
            gl2lds16(wlb + t2 + woff, (char*)&Wbs[cur ^ 1][1][0] + w64 * 16);
            gl2lds16(catb + tc + coff0, (char*)&Cbs[cur ^ 1][0] + w64 * 16);
            gl2lds16(catb + tc + coff1, (char*)&Cbs[cur ^ 1][0] + (256 + w64) * 16);
        }

        float4 c0 = *(const float4*)((const char*)&Cbs[cur][0] + cch0);
        float4 c1 = *(const float4*)((const char*)&Cbs[cur][0] + cch1);
        float fv[8] = {c0.x, c0.y, c0.z, c0.w, c1.x, c1.y, c1.z, c1.w};
        s8v ah, al;
#pragma unroll
        for (int i = 0; i < 8; i++) {
            unsigned short h, l;
            bf16split(fv[i], &h, &l);
            ah[i] = (short)h;
            al[i] = (short)l;
        }
#pragma unroll
        for (int c4 = 0; c4 < 4; c4++) {
            s8v wh = *(const s8v*)((const char*)&Wbs[cur][0][0] + wch[c4]);
            s8v wl = *(const s8v*)((const char*)&Wbs[cur][1][0] + wch[c4]);
            acc[c4] = __builtin_amdgcn_mfma_f32_16x16x32_bf16(ah, wh, acc[c4], 0, 0, 0);
            acc[c4] = __builtin_amdgcn_mfma_f32_16x16x32_bf16(ah, wl, acc[c4], 0, 0, 0);
            acc[c4] = __builtin_amdgcn_mfma_f32_16x16x32_bf16(al, wh, acc[c4], 0, 0, 0);
        }
        __syncthreads();
    }

#pragma unroll
    for (int c4 = 0; c4 < 4; c4++) {
        int o = ob0 + c4 * 16 + n;
        float sv = shf[o];
#pragma unroll
        for (int r = 0; r < 4; r++) {
            int pt = p0b + w * 16 + quad * 4 + r;
            float y = acc[c4][r] + sv;
            y = y >= 0.f ? y : 0.2f * y;
            Y[((long)b * 512 + o) * N_PTS + pt] = y;
        }
    }
}

// ---------------------------------------------------------------------------
// Weight folding to bf16 hi/lo, [o][c] layout.
// ---------------------------------------------------------------------------
__global__ void fold_edge_bf16(const float* __restrict__ W, const float* __restrict__ g,
                               const float* __restrict__ bb, const float* __restrict__ m,
                               const float* __restrict__ v,
                               unsigned short* __restrict__ Wqh, unsigned short* __restrict__ Wql,
                               unsigned short* __restrict__ Wph, unsigned short* __restrict__ Wpl,
                               float* __restrict__ shift, int C, int cout)
{
    int id = blockIdx.x * 256 + threadIdx.x;
    if (id < C * cout) {
        int o = id / C;
        int c = id % C;
        float sc = g[o] * rsqrtf(v[o] + EPSB);
        float wd = W[(long)o * 2 * C + c];
        float wc = W[(long)o * 2 * C + C + c];
        bf16split(sc * wd, &Wqh[id], &Wql[id]);
        bf16split(sc * (wc - wd), &Wph[id], &Wpl[id]);
    }
    if (id < cout) {
        float sc = g[id] * rsqrtf(v[id] + EPSB);
        shift[id] = bb[id] - m[id] * sc;
    }
}

__global__ void fold_plain_bf16(const float* __restrict__ W, const float* __restrict__ g,
                                const float* __restrict__ bb, const float* __restrict__ m,
                                const float* __restrict__ v,
                                unsigned short* __restrict__ W4h, unsigned short* __restrict__ W4l,
                                float* __restrict__ shift, int C, int cout)
{
    int id = blockIdx.x * 256 + threadIdx.x;
    if (id < C * cout) {
        int o = id / C;
        int c = id % C;
        float sc = g[o] * rsqrtf(v[o] + EPSB);
        bf16split(sc * W[(long)o * C + c], &W4h[id], &W4l[id]);
    }
    if (id < cout) {
        float sc = g[id] * rsqrtf(v[id] + EPSB);
        shift[id] = bb[id] - m[id] * sc;
    }
}

// ---------------------------------------------------------------------------
// Gather+max writing cat slice AND (optionally) next stage's G arrays + xx.
// ---------------------------------------------------------------------------
__global__ void gather_max_fused(const float* __restrict__ q, const float* __restrict__ p,
                                 const int* __restrict__ idx, float* __restrict__ cat,
                                 int cout, int c_off,
                                 unsigned short* __restrict__ Ghi,
                                 unsigned short* __restrict__ Glo,
                                 float* __restrict__ xx)
{
    int b = blockIdx.y;
    int i = blockIdx.x * 4 + threadIdx.y;
    int tx = threadIdx.x;
    const int* ip = idx + ((long)b * N_PTS + i) * KNN;
    int js[KNN];
#pragma unroll
    for (int k = 0; k < KNN; k++) js[k] = ip[k];
    const float* qb = q + (long)b * N_PTS * cout;
    const float* pb = p + ((long)b * N_PTS + i) * cout;
    float* ob = cat + ((long)b * N_PTS + i) * 512 + c_off;
    float ssum = 0.f;
    for (int o0 = 0; o0 < cout; o0 += 64) {
        int o = o0 + tx;
        float pv = pb[o];
        float mx = -FLT_MAX;
#pragma unroll
        for (int k = 0; k < KNN; k++) {
            float val = qb[(long)js[k] * cout + o] + pv;
            val = val >= 0.f ? val : 0.2f * val;
            mx = fmaxf(mx, val);
        }
        ob[o] = mx;
        if (Ghi) {
            unsigned short h, l;
            bf16split(mx, &h, &l);
            long go = ((long)b * N_PTS + i) * cout + o;
            Ghi[go] = h;
            Glo[go] = l;
            ssum = fmaf(mx, mx, ssum);
        }
    }
    if (Ghi) {
#pragma unroll
        for (int off = 32; off > 0; off >>= 1) ssum += __shfl_xor(ssum, off);
        if (tx == 0) xx[(long)b * N_PTS + i] = ssum;
    }
}

// ---------------------------------------------------------------------------
// Block-0 edge conv, fused: cat slice + G arrays (KDP=64) + xx in one pass.
// ---------------------------------------------------------------------------
__global__ void edge0_fused(const float* __restrict__ x, const int* __restrict__ idx,
                            const float* __restrict__ W0, const float* __restrict__ g0,
                            const float* __restrict__ b0, const float* __restrict__ m0,
                            const float* __restrict__ v0, float* __restrict__ cat,
                            unsigned short* __restrict__ Ghi,
                            unsigned short* __restrict__ Glo,
                            float* __restrict__ xx)
{
    int b = blockIdx.y;
    int i = blockIdx.x * 4 + threadIdx.y;
    int o = threadIdx.x;
    const float* xc = x + ((long)b * N_PTS + i) * 3;
    float cx = xc[0], cy = xc[1], cz = xc[2];
    float w[9];
#pragma unroll
    for (int c = 0; c < 9; c++) w[c] = W0[o * 9 + c];
    float sc = g0[o] * rsqrtf(v0[o] + EPSB);
    float sh = b0[o] - m0[o] * sc;
    const int* ip = idx + ((long)b * N_PTS + i) * KNN;
    float mx = -FLT_MAX;
#pragma unroll
    for (int k = 0; k < KNN; k++) {
        const float* xn = x + ((long)b * N_PTS + ip[k]) * 3;
        float nx = xn[0], ny = xn[1], nz = xn[2];
        float dx = nx - cx, dy = ny - cy, dz = nz - cz;
        float crx = cy * nz - cz * ny;
        float cry = cz * nx - cx * nz;
        float crz = cx * ny - cy * nx;
        float y = w[0] * dx + w[1] * dy + w[2] * dz
                + w[3] * crx + w[4] * cry + w[5] * crz
                + w[6] * cx + w[7] * cy + w[8] * cz;
        y = y * sc + sh;
        y = y >= 0.f ? y : 0.2f * y;
        mx = fmaxf(mx, y);
    }
    cat[((long)b * N_PTS + i) * 512 + o] = mx;
    unsigned short h, l;
    bf16split(mx, &h, &l);
    long go = ((long)b * N_PTS + i) * 64 + o;
    Ghi[go] = h;
    Glo[go] = l;
    float ssum = mx * mx;
#pragma unroll
    for (int off = 32; off > 0; off >>= 1) ssum += __shfl_xor(ssum, off);
    if (o == 0) xx[(long)b * N_PTS + i] = ssum;
}

__global__ void rowmax_kernel(const float* __restrict__ Y, float* __restrict__ ymax)
{
    __shared__ float red[256];
    int b = blockIdx.y, o = blockIdx.x, t = threadIdx.x;
    const float* yb = Y + ((long)b * 512 + o) * N_PTS;
    float mx = -FLT_MAX;
#pragma unroll
    for (int s = 0; s < N_PTS / 256; s++) mx = fmaxf(mx, yb[t + 256 * s]);
    red[t] = mx;
    __syncthreads();
    for (int off = 128; off > 0; off >>= 1) {
        if (t < off) red[t] = fmaxf(red[t], red[t + off]);
        __syncthreads();
    }
    if (t == 0) ymax[(long)b * 512 + o] = red[0];
}

__global__ void head_kernel(const float* __restrict__ ymax, const float* __restrict__ We,
                            const float* __restrict__ Wh, const float* __restrict__ bh,
                            float* __restrict__ out)
{
    __shared__ float emb[128];
    __shared__ float yv[512];
    int b = blockIdx.x, t = threadIdx.x;
    for (int s = t; s < 512; s += 128) yv[s] = ymax[(long)b * 512 + s];
    __syncthreads();
    float acc = 0.f;
    for (int c = 0; c < 512; c++) acc = fmaf(yv[c], We[(long)t * 512 + c], acc);
    emb[t] = acc;
    __syncthreads();
    float acc2 = bh[t];
    for (int ff = 0; ff < 128; ff++) acc2 = fmaf(emb[ff], Wh[(long)t * 128 + ff], acc2);
    out[(long)b * 128 + t] = acc2;
}

// ---------------------------------------------------------------------------
extern "C" void kernel_launch(void* const* d_in, const int* in_sizes, int n_in,
                              void* d_out, int out_size, void* d_ws, size_t ws_size,
                              hipStream_t stream)
{
    const float* x = (const float*)d_in[0];
    const float *W[5], *g[5], *bb[5], *m[5], *v[5];
    for (int li = 0; li < 5; li++) {
        W[li]  = (const float*)d_in[1 + li * 5 + 0];
        g[li]  = (const float*)d_in[1 + li * 5 + 1];
        bb[li] = (const float*)d_in[1 + li * 5 + 2];
        m[li]  = (const float*)d_in[1 + li * 5 + 3];
        v[li]  = (const float*)d_in[1 + li * 5 + 4];
    }
    const float* We = (const float*)d_in[26];
    const float* Wh = (const float*)d_in[27];
    const float* bh = (const float*)d_in[28];
    float* out = (float*)d_out;

    // workspace carve (float units). cat POINT-MAJOR [b][pt][512].
    float* ws   = (float*)d_ws;
    float* cat  = ws;                                   // 8,388,608
    float* qbuf = cat + (long)8388608;                  // 8,388,608 multi-purpose; stage-4 Y
    float* pbuf = qbuf + (long)8388608;                 // 4,194,304 (p-values)
    int*   idxb = (int*)(pbuf + 4194304);               // 327,680 ints
    float* xx   = (float*)(idxb + 327680);              // 16,384
    unsigned short* Wqh = (unsigned short*)(xx + 16384);// 32,768 shorts each
    unsigned short* Wql = Wqh + 32768;
    unsigned short* Wph = Wql + 32768;
    unsigned short* Wpl = Wph + 32768;
    unsigned short* W4h = Wpl + 32768;                  // 262,144 shorts
    unsigned short* W4l = W4h + 262144;
    float* shf  = (float*)(W4l + 262144);               // 512
    float* ymax = shf + 512;                            // 2,048
    // qbuf internal: Ghi/Glo 2,097,152 floats-equiv; knn lists NSL=8:
    //   knnd 2,621,440 floats + knni 2,621,440 ints = 7,340,032 total <= 8M ok
    unsigned short* Ghi = (unsigned short*)qbuf;
    unsigned short* Glo = Ghi + 2097152;
    float* knnd = qbuf + 2097152;                       // 2,621,440 floats
    int*   knni = (int*)(qbuf + 2097152 + 2621440);     // 2,621,440 ints
    float* qv   = qbuf + 2097152;                       // 4,194,304 floats (after knn)
    float* Ybuf = qbuf;                                 // stage-4 Y (all qbuf dead)

    // ---- stage 0: knn on coords, straight from x ----
    sqnorm_pm<<<dim3(16, NB), dim3(256), 0, stream>>>(x, xx, 3, 3, (long)3 * N_PTS);
    to_bf16_pm<<<dim3(64, NB), dim3(256), 0, stream>>>(
        x, (long)3 * N_PTS, 3, 3, 32, Ghi, Glo);
    fused_knn_mfma8<32><<<dim3(64, NSL, NB), dim3(256), 0, stream>>>(
        Ghi, Glo, xx, knnd, knni);
    knn_merge8<<<dim3(64), dim3(256), 0, stream>>>(knnd, knni, idxb);
    edge0_fused<<<dim3(N_PTS / 4, NB), dim3(64, 4), 0, stream>>>(
        x, idxb, W[0], g[0], bb[0], m[0], v[0], cat, Ghi, Glo, xx);

    // ---- stages 1..3 ----
    const int Cs_[3]   = {64, 64, 128};
    const int co_[3]   = {64, 128, 256};
    const int outO_[3] = {64, 128, 256};
    for (int s = 0; s < 3; s++) {
        int C = Cs_[s], cout = co_[s];
        if (C == 64)
            fused_knn_mfma8<64><<<dim3(64, NSL, NB), dim3(256), 0, stream>>>(
                Ghi, Glo, xx, knnd, knni);
        else
            fused_knn_mfma8<128><<<dim3(64, NSL, NB), dim3(256), 0, stream>>>(
                Ghi, Glo, xx, knnd, knni);
        knn_merge8<<<dim3(64), dim3(256), 0, stream>>>(knnd, knni, idxb);

        int li = s + 1;
        fold_edge_bf16<<<dim3((C * cout + 255) / 256), dim3(256), 0, stream>>>(
            W[li], g[li], bb[li], m[li], v[li], Wqh, Wql, Wph, Wpl, shf, C, cout);
        if (C == 64)
            qp_mfma<64><<<dim3(64, cout / 64, NB), dim3(256), 0, stream>>>(
                Ghi, Glo, Wqh, Wql, Wph, Wpl, shf, qv, pbuf, cout);
        else
            qp_mfma<128><<<dim3(64, cout / 64, NB), dim3(256), 0, stream>>>(
                Ghi, Glo, Wqh, Wql, Wph, Wpl, shf, qv, pbuf, cout);
        if (s < 2)
            gather_max_fused<<<dim3(N_PTS / 4, NB), dim3(64, 4), 0, stream>>>(
                qv, pbuf, idxb, cat, cout, outO_[s], Ghi, Glo, xx);
        else
            gather_max_fused<<<dim3(N_PTS / 4, NB), dim3(64, 4), 0, stream>>>(
                qv, pbuf, idxb, cat, cout, outO_[s],
                (unsigned short*)nullptr, (unsigned short*)nullptr, (float*)nullptr);
    }

    // ---- stage 4: LDS-staged MFMA conv ----
    fold_plain_bf16<<<dim3((512 * 512 + 255) / 256), dim3(256), 0, stream>>>(
        W[4], g[4], bb[4], m[4], v[4], W4h, W4l, shf, 512, 512);
    conv4h_mfma<<<dim3(N_PTS / 64, 8, NB), dim3(256), 0, stream>>>(
        cat, W4h, W4l, shf, Ybuf);

    // ---- global max + head ----
    rowmax_kernel<<<dim3(512, NB), dim3(256), 0, stream>>>(Ybuf, ymax);
    head_kernel<<<dim3(NB), dim3(128), 0, stream>>>(ymax, We, Wh, bh, out);
}

// Round 23
// 942.288 us; speedup vs baseline: 1.0780x; 1.0780x over previous
//
#include <hip/hip_runtime.h>
#include <cfloat>

#define N_PTS 4096
#define NB    4
#define KNN   20
#define EPSB  1e-5f
#define NSL   4          // knn candidate slices per batch-row (R22: NSL=8 regressed net)

typedef short s8v __attribute__((ext_vector_type(8)));
typedef float f4v __attribute__((ext_vector_type(4)));

// ---------------------------------------------------------------------------
// bf16 hi/lo split (round-to-nearest-even both halves)
// ---------------------------------------------------------------------------
__device__ __forceinline__ void bf16split(float x, unsigned short* h, unsigned short* l)
{
    unsigned u = __builtin_bit_cast(unsigned, x);
    unsigned hb = (u + 0x7fffu + ((u >> 16) & 1u)) >> 16;
    float hf = __builtin_bit_cast(float, hb << 16);
    float res = x - hf;
    unsigned u2 = __builtin_bit_cast(unsigned, res);
    unsigned lb = (u2 + 0x7fffu + ((u2 >> 16) & 1u)) >> 16;
    *h = (unsigned short)hb;
    *l = (unsigned short)lb;
}

// ---------------------------------------------------------------------------
// Packed key: fp32 distance (top 24 bits) | 8-bit lane-local ordinal.
// 15 mantissa bits: R10's 11-bit variant FAILED (0.44); this passed (0.03).
// ---------------------------------------------------------------------------
__device__ __forceinline__ unsigned packkey(float d, int lc)
{
    d = fmaxf(d, 0.f);
    unsigned u = __builtin_bit_cast(unsigned, d);
    return (u & 0xFFFFFF00u) | (unsigned)lc;
}

// Branch-free sorted-insert: ascending bubble, 20x (v_min_u32 + v_max_u32).
__device__ __forceinline__ void insert20k(unsigned key, unsigned (&k20)[KNN])
{
#pragma unroll
    for (int j = 0; j < KNN; j++) {
        unsigned old = k20[j];
        unsigned lo = old < key ? old : key;
        key = old < key ? key : old;
        k20[j] = lo;
    }
}

// async global->LDS, 16B per lane; LDS dest = wave-uniform base + lane*16
__device__ __forceinline__ void gl2lds16(const void* g, void* l)
{
    __builtin_amdgcn_global_load_lds(
        (const __attribute__((address_space(1))) unsigned int*)g,
        (__attribute__((address_space(3))) unsigned int*)l,
        16, 0, 0);
}

// 16B-chunk swizzle (involution): chunk g lives at LDS chunk g ^ f(g).
__device__ __forceinline__ int swz(int g)
{
    return g ^ (((g >> 3) ^ (g >> 6)) & 7);
}

// ---------------------------------------------------------------------------
// Point-major fp32 -> bf16 hi/lo (stage-0 only: x, C=3 -> KDP=32).
// ---------------------------------------------------------------------------
__global__ __launch_bounds__(256)
void to_bf16_pm(const float* __restrict__ F, long bsF, int ldF, int C, int KDP,
                unsigned short* __restrict__ Ghi, unsigned short* __restrict__ Glo)
{
    int b = blockIdx.y;
    int n = blockIdx.x * 64 + (threadIdx.x & 63);
    int kq = threadIdx.x >> 6;
    const float* Fr = F + (long)b * bsF + (long)n * ldF;
    for (int k0 = kq * 8; k0 < KDP; k0 += 32) {
        s8v hv, lv;
#pragma unroll
        for (int i = 0; i < 8; i++) {
            int k = k0 + i;
            float x = (k < C) ? Fr[k] : 0.f;
            unsigned short h, l;
            bf16split(x, &h, &l);
            hv[i] = (short)h;
            lv[i] = (short)l;
        }
        long o = ((long)b * N_PTS + n) * KDP + k0;
        *(s8v*)&Ghi[o] = hv;
        *(s8v*)&Glo[o] = lv;
    }
}

__global__ void sqnorm_pm(const float* __restrict__ F, float* __restrict__ xx,
                          int C, int ldF, long bsF)
{
    int b = blockIdx.y;
    int i = blockIdx.x * 256 + threadIdx.x;
    const float* r = F + (long)b * bsF + (long)i * ldF;
    float s = 0.f;
    for (int c = 0; c < C; c++) s = fmaf(r[c], r[c], s);
    xx[(long)b * N_PTS + i] = s;
}

// ---------------------------------------------------------------------------
// MFMA fused distance + top-20, LDS-staged + XOR swizzle (R17/R21 config —
// best measured; R22's NSL=8/LDS-union variant improved knn<128> by only
// 4 us (issue-floor) while doubling per-block fixed costs -> net regression).
// ---------------------------------------------------------------------------
template<int KDP>
__global__ __launch_bounds__(256, 3)
void fused_knn_mfma7(const unsigned short* __restrict__ Ghi,
                     const unsigned short* __restrict__ Glo,
                     const float* __restrict__ xx,
                     float* __restrict__ knnd, int* __restrict__ knni)
{
    constexpr int KS = KDP / 32;
    constexpr int TS = 16 * KDP;
    constexpr int NCH = (TS * 2) / 16;
    __shared__ short cbuf[2][2][TS];
    __shared__ unsigned mk[4][16][4][KNN];

    int tid = threadIdx.x;
    int w = tid >> 6, L = tid & 63;
    int n = L & 15;
    int quad = L >> 4;
    int b = blockIdx.z, slice = blockIdx.y;
    int q0 = blockIdx.x * 64, qw = w * 16;
    const unsigned short* Gh = Ghi + (long)b * N_PTS * KDP;
    const unsigned short* Gl = Glo + (long)b * N_PTS * KDP;
    const float* xxb = xx + (long)b * N_PTS;

    s8v qhi[KS], qlo[KS];
    long qbase = (long)(q0 + qw + n) * KDP + quad * 8;
#pragma unroll
    for (int ks = 0; ks < KS; ks++) {
        qhi[ks] = *(const s8v*)&Gh[qbase + ks * 32];
        qlo[ks] = *(const s8v*)&Gl[qbase + ks * 32];
    }
    float xq = xxb[q0 + qw + n];

    unsigned k20[KNN];
#pragma unroll
    for (int j = 0; j < KNN; j++) k20[j] = 0xFFFFFFFFu;

    int po[KS];
#pragma unroll
    for (int ks = 0; ks < KS; ks++) {
        int gL = n * (KDP / 8) + quad + ks * 4;
        po[ks] = swz(gL) * 8;
    }
    int gsrc = swz(tid);

    int w64 = tid & 192;
    {
        long tb = (long)(slice * 1024) * KDP;
        if (tid < NCH) {
            gl2lds16((const char*)(Gh + tb) + gsrc * 16,
                     (char*)&cbuf[0][0][0] + w64 * 16);
            gl2lds16((const char*)(Gl + tb) + gsrc * 16,
                     (char*)&cbuf[0][1][0] + w64 * 16);
        }
    }
    __syncthreads();

    const float* xcp = xxb + slice * 1024 + quad * 4;

    for (int t = 0; t < 64; t++) {
        int cur = t & 1;
        if (t < 63 && tid < NCH) {
            long tb = (long)(slice * 1024 + (t + 1) * 16) * KDP;
            gl2lds16((const char*)(Gh + tb) + gsrc * 16,
                     (char*)&cbuf[cur ^ 1][0][0] + w64 * 16);
            gl2lds16((const char*)(Gl + tb) + gsrc * 16,
                     (char*)&cbuf[cur ^ 1][1][0] + w64 * 16);
        }

        const short* Ch = &cbuf[cur][0][0];
        const short* Cl = &cbuf[cur][1][0];
        f4v acc = {0.f, 0.f, 0.f, 0.f};
#pragma unroll
        for (int ks = 0; ks < KS; ks++) {
            s8v chi = *(const s8v*)&Ch[po[ks]];
            s8v clo = *(const s8v*)&Cl[po[ks]];
            acc = __builtin_amdgcn_mfma_f32_16x16x32_bf16(chi, qhi[ks], acc, 0, 0, 0);
            acc = __builtin_amdgcn_mfma_f32_16x16x32_bf16(chi, qlo[ks], acc, 0, 0, 0);
            acc = __builtin_amdgcn_mfma_f32_16x16x32_bf16(clo, qhi[ks], acc, 0, 0, 0);
        }
        float4 xc4 = *(const float4*)xcp;
        float xcv[4] = {xc4.x, xc4.y, xc4.z, xc4.w};
#pragma unroll
        for (int r = 0; r < 4; r++) {
            float d = xq + xcv[r] - 2.f * acc[r];
            insert20k(packkey(d, t * 4 + r), k20);
        }
        xcp += 16;
        __syncthreads();
    }

#pragma unroll
    for (int j = 0; j < KNN; j++) mk[w][n][quad][j] = k20[j];
    __syncthreads();
    if (L < 16) {
        int p[4] = {0, 0, 0, 0};
        long o = (((long)b * NSL + slice) * N_PTS + (q0 + qw + L)) * KNN;
#pragma unroll
        for (int j = 0; j < KNN; j++) {
            unsigned bd = 0xFFFFFF00u; int bi = 0x7fffffff; int bq = 0;
#pragma unroll
            for (int qd = 0; qd < 4; qd++) {
                unsigned kk = mk[w][L][qd][p[qd]];
                unsigned db = kk & 0xFFFFFF00u;
                int lc = (int)(kk & 0xFFu);
                int ci = slice * 1024 + (lc >> 2) * 16 + qd * 4 + (lc & 3);
                if (db < bd || (db == bd && ci < bi)) { bd = db; bi = ci; bq = qd; }
            }
            knnd[o + j] = __builtin_bit_cast(float, bd);
            knni[o + j] = bi;
            p[bq]++;
        }
    }
}

// ---------------------------------------------------------------------------
__global__ void knn_merge4(const float* __restrict__ knnd, const int* __restrict__ knni,
                           int* __restrict__ idxOut)
{
    int id = blockIdx.x * 256 + threadIdx.x;
    int b = id / N_PTS, i = id % N_PTS;
    const float* dl[NSL]; const int* il[NSL];
#pragma unroll
    for (int qt = 0; qt < NSL; qt++) {
        dl[qt] = knnd + (((long)b * NSL + qt) * N_PTS + i) * KNN;
        il[qt] = knni + (((long)b * NSL + qt) * N_PTS + i) * KNN;
    }
    int p[NSL];
#pragma unroll
    for (int qt = 0; qt < NSL; qt++) p[qt] = 0;
    int* o = idxOut + (long)id * KNN;
#pragma unroll
    for (int j = 0; j < KNN; j++) {
        float best = FLT_MAX; int bi = 0x7fffffff; int bq = 0;
#pragma unroll
        for (int qt = 0; qt < NSL; qt++) {
            float vv = (p[qt] < KNN) ? dl[qt][p[qt]] : FLT_MAX;
            int   ci = (p[qt] < KNN) ? il[qt][p[qt]] : 0x7fffffff;
            if (vv < best || (vv == best && ci < bi)) { best = vv; bi = ci; bq = qt; }
        }
        o[j] = bi;
        p[bq]++;
    }
}

// ---------------------------------------------------------------------------
// Fused q/p MFMA GEMM (edge stages) — unchanged.
// ---------------------------------------------------------------------------
template<int KDP>
__global__ __launch_bounds__(256)
void qp_mfma(const unsigned short* __restrict__ Ghi,
             const unsigned short* __restrict__ Glo,
             const unsigned short* __restrict__ Wqh, const unsigned short* __restrict__ Wql,
             const unsigned short* __restrict__ Wph, const unsigned short* __restrict__ Wpl,
             const float* __restrict__ shf,
             float* __restrict__ qv, float* __restrict__ pv, int cout)
{
    constexpr int KS = KDP / 32;
    int tid = threadIdx.x;
    int w = tid >> 6, L = tid & 63;
    int n = L & 15, quad = L >> 4;
    int b = blockIdx.z;
    int p0 = blockIdx.x * 64 + w * 16;

    s8v ah[KS], al[KS];
    long abase = ((long)b * N_PTS + p0 + n) * KDP + quad * 8;
#pragma unroll
    for (int ks = 0; ks < KS; ks++) {
        ah[ks] = *(const s8v*)&Ghi[abase + ks * 32];
        al[ks] = *(const s8v*)&Glo[abase + ks * 32];
    }

#pragma unroll
    for (int oc4 = 0; oc4 < 4; oc4++) {
        int oc = blockIdx.y * 4 + oc4;
        long wbase = (long)(oc * 16 + n) * KDP + quad * 8;
        f4v aq = {0.f, 0.f, 0.f, 0.f};
        f4v ap = {0.f, 0.f, 0.f, 0.f};
#pragma unroll
        for (int ks = 0; ks < KS; ks++) {
            s8v wh = *(const s8v*)&Wqh[wbase + ks * 32];
            s8v wl = *(const s8v*)&Wql[wbase + ks * 32];
            aq = __builtin_amdgcn_mfma_f32_16x16x32_bf16(ah[ks], wh, aq, 0, 0, 0);
            aq = __builtin_amdgcn_mfma_f32_16x16x32_bf16(ah[ks], wl, aq, 0, 0, 0);
            aq = __builtin_amdgcn_mfma_f32_16x16x32_bf16(al[ks], wh, aq, 0, 0, 0);
            s8v ph = *(const s8v*)&Wph[wbase + ks * 32];
            s8v pl = *(const s8v*)&Wpl[wbase + ks * 32];
            ap = __builtin_amdgcn_mfma_f32_16x16x32_bf16(ah[ks], ph, ap, 0, 0, 0);
            ap = __builtin_amdgcn_mfma_f32_16x16x32_bf16(ah[ks], pl, ap, 0, 0, 0);
            ap = __builtin_amdgcn_mfma_f32_16x16x32_bf16(al[ks], ph, ap, 0, 0, 0);
        }
        float sv = shf[oc * 16 + n];
#pragma unroll
        for (int r = 0; r < 4; r++) {
            long pt = p0 + quad * 4 + r;
            long o = ((long)b * N_PTS + pt) * cout + oc * 16 + n;
            qv[o] = aq[r];
            pv[o] = ap[r] + sv;
        }
    }
}

// ---------------------------------------------------------------------------
// Stage-4 conv, LDS double-buffered W + cat tiles (R21, unchanged).
// ---------------------------------------------------------------------------
__global__ __launch_bounds__(256)
void conv4h_mfma(const float* __restrict__ cat,
                 const unsigned short* __restrict__ W4h, const unsigned short* __restrict__ W4l,
                 const float* __restrict__ shf, float* __restrict__ Y)
{
    __shared__ short Wbs[2][2][2048];
    __shared__ float Cbs[2][2048];

    int tid = threadIdx.x;
    int w = tid >> 6, L = tid & 63;
    int n = L & 15, quad = L >> 4;
    int b = blockIdx.z;
    int p0b = blockIdx.x * 64;
    int ob0 = blockIdx.y * 64;
    int w64 = tid & 192;

    const char* catb = (const char*)(cat + ((long)b * N_PTS + p0b) * 512);
    const char* whb  = (const char*)(W4h + (long)ob0 * 512);
    const char* wlb  = (const char*)(W4l + (long)ob0 * 512);

    int gw = swz(tid);
    int gc0 = swz(tid);
    int gc1 = swz(tid + 256);

    long woff = (long)(gw >> 2) * 1024 + (gw & 3) * 16;
    long coff0 = (long)(gc0 >> 3) * 2048 + (gc0 & 7) * 16;
    long coff1 = (long)(gc1 >> 3) * 2048 + (gc1 & 7) * 16;

    {
        gl2lds16(whb + woff, (char*)&Wbs[0][0][0] + w64 * 16);
        gl2lds16(wlb + woff, (char*)&Wbs[0][1][0] + w64 * 16);
        gl2lds16(catb + coff0, (char*)&Cbs[0][0] + w64 * 16);
        gl2lds16(catb + coff1, (char*)&Cbs[0][0] + (256 + w64) * 16);
    }
    __syncthreads();

    int p8 = (w * 16 + n) * 8;
    int cch0 = swz(p8 + quad * 2) * 16;
    int cch1 = swz(p8 + quad * 2 + 1) * 16;
    int wch[4];
#pragma unroll
    for (int c4 = 0; c4 < 4; c4++) wch[c4] = swz((c4 * 16 + n) * 4 + quad) * 16;

    f4v acc[4];
#pragma unroll
    for (int c4 = 0; c4 < 4; c4++) acc[c4] = {0.f, 0.f, 0.f, 0.f};

    for (int ks = 0; ks < 16; ks++) {
        int cur = ks & 1;
        if (ks < 15) {
            long t2 = (long)(ks + 1) * 64;
            long tc = (long)(ks + 1) * 128;
            gl2lds16(whb + t2 + woff, (char*)&Wbs[cur ^ 1][0][0] + w64 * 16);
            gl2lds16(wlb + t2 + woff, (char*)&Wbs[cur ^ 1][1][0] + w64 * 16);
            gl2lds16(catb + tc + coff0, (char*)&Cbs[cur ^ 1][0] + w64 * 16);
            gl2lds16(catb + tc + coff1, (char*)&Cbs[cur ^ 1][0] + (256 + w64) * 16);
        }

        float4 c0 = *(const float4*)((const char*)&Cbs[cur][0] + cch0);
        float4 c1 = *(const float4*)((const char*)&Cbs[cur][0] + cch1);
        float fv[8] = {c0.x, c0.y, c0.z, c0.w, c1.x, c1.y, c1.z, c1.w};
        s8v ah, al;
#pragma unroll
        for (int i = 0; i < 8; i++) {
            unsigned short h, l;
            bf16split(fv[i], &h, &l);
            ah[i] = (short)h;
            al[i] = (short)l;
        }
#pragma unroll
        for (int c4 = 0; c4 < 4; c4++) {
            s8v wh = *(const s8v*)((const char*)&Wbs[cur][0][0] + wch[c4]);
            s8v wl = *(const s8v*)((const char*)&Wbs[cur][1][0] + wch[c4]);
            acc[c4] = __builtin_amdgcn_mfma_f32_16x16x32_bf16(ah, wh, acc[c4], 0, 0, 0);
            acc[c4] = __builtin_amdgcn_mfma_f32_16x16x32_bf16(ah, wl, acc[c4], 0, 0, 0);
            acc[c4] = __builtin_amdgcn_mfma_f32_16x16x32_bf16(al, wh, acc[c4], 0, 0, 0);
        }
        __syncthreads();
    }

#pragma unroll
    for (int c4 = 0; c4 < 4; c4++) {
        int o = ob0 + c4 * 16 + n;
        float sv = shf[o];
#pragma unroll
        for (int r = 0; r < 4; r++) {
            int pt = p0b + w * 16 + quad * 4 + r;
            float y = acc[c4][r] + sv;
            y = y >= 0.f ? y : 0.2f * y;
            Y[((long)b * 512 + o) * N_PTS + pt] = y;
        }
    }
}

// ---------------------------------------------------------------------------
// Weight folding to bf16 hi/lo, [o][c] layout.
// ---------------------------------------------------------------------------
__global__ void fold_edge_bf16(const float* __restrict__ W, const float* __restrict__ g,
                               const float* __restrict__ bb, const float* __restrict__ m,
                               const float* __restrict__ v,
                               unsigned short* __restrict__ Wqh, unsigned short* __restrict__ Wql,
                               unsigned short* __restrict__ Wph, unsigned short* __restrict__ Wpl,
                               float* __restrict__ shift, int C, int cout)
{
    int id = blockIdx.x * 256 + threadIdx.x;
    if (id < C * cout) {
        int o = id / C;
        int c = id % C;
        float sc = g[o] * rsqrtf(v[o] + EPSB);
        float wd = W[(long)o * 2 * C + c];
        float wc = W[(long)o * 2 * C + C + c];
        bf16split(sc * wd, &Wqh[id], &Wql[id]);
        bf16split(sc * (wc - wd), &Wph[id], &Wpl[id]);
    }
    if (id < cout) {
        float sc = g[id] * rsqrtf(v[id] + EPSB);
        shift[id] = bb[id] - m[id] * sc;
    }
}

__global__ void fold_plain_bf16(const float* __restrict__ W, const float* __restrict__ g,
                                const float* __restrict__ bb, const float* __restrict__ m,
                                const float* __restrict__ v,
                                unsigned short* __restrict__ W4h, unsigned short* __restrict__ W4l,
                                float* __restrict__ shift, int C, int cout)
{
    int id = blockIdx.x * 256 + threadIdx.x;
    if (id < C * cout) {
        int o = id / C;
        int c = id % C;
        float sc = g[o] * rsqrtf(v[o] + EPSB);
        bf16split(sc * W[(long)o * C + c], &W4h[id], &W4l[id]);
    }
    if (id < cout) {
        float sc = g[id] * rsqrtf(v[id] + EPSB);
        shift[id] = bb[id] - m[id] * sc;
    }
}

// ---------------------------------------------------------------------------
// Gather+max writing cat slice AND (optionally) next stage's G arrays + xx.
// ---------------------------------------------------------------------------
__global__ void gather_max_fused(const float* __restrict__ q, const float* __restrict__ p,
                                 const int* __restrict__ idx, float* __restrict__ cat,
                                 int cout, int c_off,
                                 unsigned short* __restrict__ Ghi,
                                 unsigned short* __restrict__ Glo,
                                 float* __restrict__ xx)
{
    int b = blockIdx.y;
    int i = blockIdx.x * 4 + threadIdx.y;
    int tx = threadIdx.x;
    const int* ip = idx + ((long)b * N_PTS + i) * KNN;
    int js[KNN];
#pragma unroll
    for (int k = 0; k < KNN; k++) js[k] = ip[k];
    const float* qb = q + (long)b * N_PTS * cout;
    const float* pb = p + ((long)b * N_PTS + i) * cout;
    float* ob = cat + ((long)b * N_PTS + i) * 512 + c_off;
    float ssum = 0.f;
    for (int o0 = 0; o0 < cout; o0 += 64) {
        int o = o0 + tx;
        float pv = pb[o];
        float mx = -FLT_MAX;
#pragma unroll
        for (int k = 0; k < KNN; k++) {
            float val = qb[(long)js[k] * cout + o] + pv;
            val = val >= 0.f ? val : 0.2f * val;
            mx = fmaxf(mx, val);
        }
        ob[o] = mx;
        if (Ghi) {
            unsigned short h, l;
            bf16split(mx, &h, &l);
            long go = ((long)b * N_PTS + i) * cout + o;
            Ghi[go] = h;
            Glo[go] = l;
            ssum = fmaf(mx, mx, ssum);
        }
    }
    if (Ghi) {
#pragma unroll
        for (int off = 32; off > 0; off >>= 1) ssum += __shfl_xor(ssum, off);
        if (tx == 0) xx[(long)b * N_PTS + i] = ssum;
    }
}

// ---------------------------------------------------------------------------
// Block-0 edge conv, fused: cat slice + G arrays (KDP=64) + xx in one pass.
// ---------------------------------------------------------------------------
__global__ void edge0_fused(const float* __restrict__ x, const int* __restrict__ idx,
                            const float* __restrict__ W0, const float* __restrict__ g0,
                            const float* __restrict__ b0, const float* __restrict__ m0,
                            const float* __restrict__ v0, float* __restrict__ cat,
                            unsigned short* __restrict__ Ghi,
                            unsigned short* __restrict__ Glo,
                            float* __restrict__ xx)
{
    int b = blockIdx.y;
    int i = blockIdx.x * 4 + threadIdx.y;
    int o = threadIdx.x;
    const float* xc = x + ((long)b * N_PTS + i) * 3;
    float cx = xc[0], cy = xc[1], cz = xc[2];
    float w[9];
#pragma unroll
    for (int c = 0; c < 9; c++) w[c] = W0[o * 9 + c];
    float sc = g0[o] * rsqrtf(v0[o] + EPSB);
    float sh = b0[o] - m0[o] * sc;
    const int* ip = idx + ((long)b * N_PTS + i) * KNN;
    float mx = -FLT_MAX;
#pragma unroll
    for (int k = 0; k < KNN; k++) {
        const float* xn = x + ((long)b * N_PTS + ip[k]) * 3;
        float nx = xn[0], ny = xn[1], nz = xn[2];
        float dx = nx - cx, dy = ny - cy, dz = nz - cz;
        float crx = cy * nz - cz * ny;
        float cry = cz * nx - cx * nz;
        float crz = cx * ny - cy * nx;
        float y = w[0] * dx + w[1] * dy + w[2] * dz
                + w[3] * crx + w[4] * cry + w[5] * crz
                + w[6] * cx + w[7] * cy + w[8] * cz;
        y = y * sc + sh;
        y = y >= 0.f ? y : 0.2f * y;
        mx = fmaxf(mx, y);
    }
    cat[((long)b * N_PTS + i) * 512 + o] = mx;
    unsigned short h, l;
    bf16split(mx, &h, &l);
    long go = ((long)b * N_PTS + i) * 64 + o;
    Ghi[go] = h;
    Glo[go] = l;
    float ssum = mx * mx;
#pragma unroll
    for (int off = 32; off > 0; off >>= 1) ssum += __shfl_xor(ssum, off);
    if (o == 0) xx[(long)b * N_PTS + i] = ssum;
}

__global__ void rowmax_kernel(const float* __restrict__ Y, float* __restrict__ ymax)
{
    __shared__ float red[256];
    int b = blockIdx.y, o = blockIdx.x, t = threadIdx.x;
    const float* yb = Y + ((long)b * 512 + o) * N_PTS;
    float mx = -FLT_MAX;
#pragma unroll
    for (int s = 0; s < N_PTS / 256; s++) mx = fmaxf(mx, yb[t + 256 * s]);
    red[t] = mx;
    __syncthreads();
    for (int off = 128; off > 0; off >>= 1) {
        if (t < off) red[t] = fmaxf(red[t], red[t + off]);
        __syncthreads();
    }
    if (t == 0) ymax[(long)b * 512 + o] = red[0];
}

__global__ void head_kernel(const float* __restrict__ ymax, const float* __restrict__ We,
                            const float* __restrict__ Wh, const float* __restrict__ bh,
                            float* __restrict__ out)
{
    __shared__ float emb[128];
    __shared__ float yv[512];
    int b = blockIdx.x, t = threadIdx.x;
    for (int s = t; s < 512; s += 128) yv[s] = ymax[(long)b * 512 + s];
    __syncthreads();
    float acc = 0.f;
    for (int c = 0; c < 512; c++) acc = fmaf(yv[c], We[(long)t * 512 + c], acc);
    emb[t] = acc;
    __syncthreads();
    float acc2 = bh[t];
    for (int ff = 0; ff < 128; ff++) acc2 = fmaf(emb[ff], Wh[(long)t * 128 + ff], acc2);
    out[(long)b * 128 + t] = acc2;
}

// ---------------------------------------------------------------------------
extern "C" void kernel_launch(void* const* d_in, const int* in_sizes, int n_in,
                              void* d_out, int out_size, void* d_ws, size_t ws_size,
                              hipStream_t stream)
{
    const float* x = (const float*)d_in[0];
    const float *W[5], *g[5], *bb[5], *m[5], *v[5];
    for (int li = 0; li < 5; li++) {
        W[li]  = (const float*)d_in[1 + li * 5 + 0];
        g[li]  = (const float*)d_in[1 + li * 5 + 1];
        bb[li] = (const float*)d_in[1 + li * 5 + 2];
        m[li]  = (const float*)d_in[1 + li * 5 + 3];
        v[li]  = (const float*)d_in[1 + li * 5 + 4];
    }
    const float* We = (const float*)d_in[26];
    const float* Wh = (const float*)d_in[27];
    const float* bh = (const float*)d_in[28];
    float* out = (float*)d_out;

    // workspace carve (float units). cat POINT-MAJOR [b][pt][512].
    float* ws   = (float*)d_ws;
    float* cat  = ws;                                   // 8,388,608
    float* qbuf = cat + (long)8388608;                  // 8,388,608 multi-purpose; stage-4 Y
    float* pbuf = qbuf + (long)8388608;                 // 4,194,304 (p-values)
    int*   idxb = (int*)(pbuf + 4194304);               // 327,680 ints
    float* xx   = (float*)(idxb + 327680);              // 16,384
    unsigned short* Wqh = (unsigned short*)(xx + 16384);// 32,768 shorts each
    unsigned short* Wql = Wqh + 32768;
    unsigned short* Wph = Wql + 32768;
    unsigned short* Wpl = Wph + 32768;
    unsigned short* W4h = Wpl + 32768;                  // 262,144 shorts
    unsigned short* W4l = W4h + 262144;
    float* shf  = (float*)(W4l + 262144);               // 512
    float* ymax = shf + 512;                            // 2,048
    unsigned short* Ghi = (unsigned short*)qbuf;        // 2,097,152 shorts max
    unsigned short* Glo = Ghi + 2097152;
    float* knnd = qbuf + 2097152;                       // 1,310,720 floats
    int*   knni = (int*)(qbuf + 2097152 + 1310720);     // 1,310,720 ints
    float* qv   = qbuf + 2097152;                       // 4,194,304 floats (after knn)
    float* Ybuf = qbuf;                                 // stage-4 Y (all qbuf dead)

    // ---- stage 0: knn on coords, straight from x ----
    sqnorm_pm<<<dim3(16, NB), dim3(256), 0, stream>>>(x, xx, 3, 3, (long)3 * N_PTS);
    to_bf16_pm<<<dim3(64, NB), dim3(256), 0, stream>>>(
        x, (long)3 * N_PTS, 3, 3, 32, Ghi, Glo);
    fused_knn_mfma7<32><<<dim3(64, NSL, NB), dim3(256), 0, stream>>>(
        Ghi, Glo, xx, knnd, knni);
    knn_merge4<<<dim3(64), dim3(256), 0, stream>>>(knnd, knni, idxb);
    edge0_fused<<<dim3(N_PTS / 4, NB), dim3(64, 4), 0, stream>>>(
        x, idxb, W[0], g[0], bb[0], m[0], v[0], cat, Ghi, Glo, xx);

    // ---- stages 1..3 ----
    const int Cs_[3]   = {64, 64, 128};
    const int co_[3]   = {64, 128, 256};
    const int outO_[3] = {64, 128, 256};
    for (int s = 0; s < 3; s++) {
        int C = Cs_[s], cout = co_[s];
        if (C == 64)
            fused_knn_mfma7<64><<<dim3(64, NSL, NB), dim3(256), 0, stream>>>(
                Ghi, Glo, xx, knnd, knni);
        else
            fused_knn_mfma7<128><<<dim3(64, NSL, NB), dim3(256), 0, stream>>>(
                Ghi, Glo, xx, knnd, knni);
        knn_merge4<<<dim3(64), dim3(256), 0, stream>>>(knnd, knni, idxb);

        int li = s + 1;
        fold_edge_bf16<<<dim3((C * cout + 255) / 256), dim3(256), 0, stream>>>(
            W[li], g[li], bb[li], m[li], v[li], Wqh, Wql, Wph, Wpl, shf, C, cout);
        if (C == 64)
            qp_mfma<64><<<dim3(64, cout / 64, NB), dim3(256), 0, stream>>>(
                Ghi, Glo, Wqh, Wql, Wph, Wpl, shf, qv, pbuf, cout);
        else
            qp_mfma<128><<<dim3(64, cout / 64, NB), dim3(256), 0, stream>>>(
                Ghi, Glo, Wqh, Wql, Wph, Wpl, shf, qv, pbuf, cout);
        if (s < 2)
            gather_max_fused<<<dim3(N_PTS / 4, NB), dim3(64, 4), 0, stream>>>(
                qv, pbuf, idxb, cat, cout, outO_[s], Ghi, Glo, xx);
        else
            gather_max_fused<<<dim3(N_PTS / 4, NB), dim3(64, 4), 0, stream>>>(
                qv, pbuf, idxb, cat, cout, outO_[s],
                (unsigned short*)nullptr, (unsigned short*)nullptr, (float*)nullptr);
    }

    // ---- stage 4: LDS-staged MFMA conv ----
    fold_plain_bf16<<<dim3((512 * 512 + 255) / 256), dim3(256), 0, stream>>>(
        W[4], g[4], bb[4], m[4], v[4], W4h, W4l, shf, 512, 512);
    conv4h_mfma<<<dim3(N_PTS / 64, 8, NB), dim3(256), 0, stream>>>(
        cat, W4h, W4l, shf, Ybuf);

    // ---- global max + head ----
    rowmax_kernel<<<dim3(512, NB), dim3(256), 0, stream>>>(Ybuf, ymax);
    head_kernel<<<dim3(NB), dim3(128), 0, stream>>>(ymax, We, Wh, bh, out);
}